// Round 1
// baseline (541.905 us; speedup 1.0000x reference)
//
#include <hip/hip_runtime.h>
#include <hip/hip_bf16.h>
#include <cstdint>
#include <cstddef>

#define EPS 1e-5f

typedef __attribute__((ext_vector_type(4))) int int32x4;

// ---------------- block reduction helpers (256 threads = 4 waves) ----------------
__device__ __forceinline__ float blk_sum(float v, float* s4) {
    #pragma unroll
    for (int o = 32; o; o >>= 1) v += __shfl_down(v, o, 64);
    if ((threadIdx.x & 63) == 0) s4[threadIdx.x >> 6] = v;
    __syncthreads();
    v = s4[0] + s4[1] + s4[2] + s4[3];
    __syncthreads();
    return v;
}

__device__ __forceinline__ void blk_sum2(float& a, float& b, float* s8) {
    #pragma unroll
    for (int o = 32; o; o >>= 1) {
        a += __shfl_down(a, o, 64);
        b += __shfl_down(b, o, 64);
    }
    if ((threadIdx.x & 63) == 0) {
        s8[threadIdx.x >> 6] = a;
        s8[4 + (threadIdx.x >> 6)] = b;
    }
    __syncthreads();
    a = s8[0] + s8[1] + s8[2] + s8[3];
    b = s8[4] + s8[5] + s8[6] + s8[7];
    __syncthreads();
}

__device__ __forceinline__ float blk_max(float v, float* s4) {
    #pragma unroll
    for (int o = 32; o; o >>= 1) v = fmaxf(v, __shfl_down(v, o, 64));
    if ((threadIdx.x & 63) == 0) s4[threadIdx.x >> 6] = v;
    __syncthreads();
    v = fmaxf(fmaxf(s4[0], s4[1]), fmaxf(s4[2], s4[3]));
    __syncthreads();
    return v;
}

__device__ __forceinline__ int pack4(float a, float b, float c, float d, float lo, float hi) {
    int x0 = (int)fminf(fmaxf(a, lo), hi);
    int x1 = (int)fminf(fmaxf(b, lo), hi);
    int x2 = (int)fminf(fmaxf(c, lo), hi);
    int x3 = (int)fminf(fmaxf(d, lo), hi);
    return (x0 & 255) | ((x1 & 255) << 8) | ((x2 & 255) << 16) | ((x3 & 255) << 24);
}

__device__ __forceinline__ float bflo(unsigned u) { return __uint_as_float(u << 16); }
__device__ __forceinline__ float bfhi(unsigned u) { return __uint_as_float(u & 0xffff0000u); }

// ---------------- fused absmean over all 4 weights (1 launch) --------------------------
__global__ __launch_bounds__(256) void absmean_all_kernel(
    const float* __restrict__ W0, const float* __restrict__ W1,
    const float* __restrict__ W2, const float* __restrict__ W3,
    float* __restrict__ part) {
    __shared__ float s4[4];
    const float* w; int sidx; unsigned rel;
    unsigned bx = blockIdx.x;
    if (bx < 1024)      { w = W0; sidx = 0; rel = bx; }
    else if (bx < 5120) { w = W1; sidx = 1; rel = bx - 1024; }
    else if (bx < 9216) { w = W2; sidx = 2; rel = bx - 5120; }
    else                { w = W3; sidx = 3; rel = bx - 9216; }
    const float4* p = (const float4*)w + (size_t)rel * 1024 + threadIdx.x;
    float4 v0 = p[0], v1 = p[256], v2 = p[512], v3 = p[768];
    float s = fabsf(v0.x) + fabsf(v0.y) + fabsf(v0.z) + fabsf(v0.w)
            + fabsf(v1.x) + fabsf(v1.y) + fabsf(v1.z) + fabsf(v1.w)
            + fabsf(v2.x) + fabsf(v2.y) + fabsf(v2.z) + fabsf(v2.w)
            + fabsf(v3.x) + fabsf(v3.y) + fabsf(v3.z) + fabsf(v3.w);
    s = blk_sum(s, s4);
    if (threadIdx.x == 0) atomicAdd(&part[(sidx * 64 + (rel & 63)) * 16], s);
}

// ---------------- reduce 256 spread slots -> sums[4] ------
__global__ __launch_bounds__(256) void reduce_sums_kernel(const float* __restrict__ part,
                                                          float* __restrict__ sums) {
    int w = threadIdx.x >> 6, l = threadIdx.x & 63;
    float v = part[(w * 64 + l) * 16];
    #pragma unroll
    for (int o = 32; o; o >>= 1) v += __shfl_down(v, o, 64);
    if (l == 0) sums[w] = v;
}

// ---------------- fused ternary quantization for all 4 weights + W3 pad ----------------
__global__ __launch_bounds__(256) void wquant_all_kernel(
    const float* __restrict__ W0, const float* __restrict__ W1,
    const float* __restrict__ W2, const float* __restrict__ W3,
    int* __restrict__ q0, int* __restrict__ q1, int* __restrict__ q2, int* __restrict__ q3,
    const float* __restrict__ sums) {
    const float* w; int* q; int sidx; unsigned rel; float invN; bool pad = false;
    unsigned bx = blockIdx.x;
    if (bx < 1024)      { w = W0; q = q0; sidx = 0; rel = bx;        invN = 1.f / 4194304.f; }
    else if (bx < 5120) { w = W1; q = q1; sidx = 1; rel = bx - 1024; invN = 1.f / 16777216.f; }
    else if (bx < 9216) { w = W2; q = q2; sidx = 2; rel = bx - 5120; invN = 1.f / 16777216.f; }
    else                { w = W3; q = q3; sidx = 3; rel = bx - 9216; invN = 1.f / 8192000.f;
                          pad = (rel >= 2000); }
    int4 o = {0, 0, 0, 0};
    if (!pad) {
        float mean = fmaxf(sums[sidx] * invN, EPS);
        float scale = 1.f / mean;
        const float4* p = (const float4*)w + (size_t)rel * 1024 + threadIdx.x * 4;
        float4 v0 = p[0], v1 = p[1], v2 = p[2], v3 = p[3];
        o.x = pack4(rintf(v0.x * scale), rintf(v0.y * scale), rintf(v0.z * scale), rintf(v0.w * scale), -1.f, 1.f);
        o.y = pack4(rintf(v1.x * scale), rintf(v1.y * scale), rintf(v1.z * scale), rintf(v1.w * scale), -1.f, 1.f);
        o.z = pack4(rintf(v2.x * scale), rintf(v2.y * scale), rintf(v2.z * scale), rintf(v2.w * scale), -1.f, 1.f);
        o.w = pack4(rintf(v3.x * scale), rintf(v3.y * scale), rintf(v3.z * scale), rintf(v3.w * scale), -1.f, 1.f);
    }
    ((int4*)q)[(size_t)rel * 256 + threadIdx.x] = o;
}

// ---------------- input activation quantization (D = 1024) ----------------
__global__ __launch_bounds__(256) void actquant_kernel(const float* __restrict__ x,
                                                       int* __restrict__ q,
                                                       float* __restrict__ inv_s) {
    __shared__ float s4[4];
    int row = blockIdx.x;
    const float4* xr = (const float4*)(x + (size_t)row * 1024);
    float4 v = xr[threadIdx.x];
    float m = fmaxf(fmaxf(fabsf(v.x), fabsf(v.y)), fmaxf(fabsf(v.z), fabsf(v.w)));
    m = blk_max(m, s4);
    m = fmaxf(m, EPS);
    float scale = 127.f / m;
    if (threadIdx.x == 0) inv_s[row] = m / 127.f;
    q[(size_t)row * 256 + threadIdx.x] =
        pack4(rintf(v.x * scale), rintf(v.y * scale),
              rintf(v.z * scale), rintf(v.w * scale), -128.f, 127.f);
}

// ---------------- fused LayerNorm + SiLU + act quant, bf16 input (H = 4096) ------------
__global__ __launch_bounds__(256) void ln_silu_quant_kernel(const ushort* __restrict__ h,
                                                            const float* __restrict__ g,
                                                            const float* __restrict__ b,
                                                            int* __restrict__ q,
                                                            float* __restrict__ inv_s) {
    __shared__ float s8[8];
    int row = blockIdx.x;
    int t = threadIdx.x;
    const uint4* hr = (const uint4*)(h + (size_t)row * 4096);
    uint4 p0 = hr[t * 2], p1 = hr[t * 2 + 1];
    float f[16];
    f[0] = bflo(p0.x); f[1] = bfhi(p0.x); f[2] = bflo(p0.y); f[3] = bfhi(p0.y);
    f[4] = bflo(p0.z); f[5] = bfhi(p0.z); f[6] = bflo(p0.w); f[7] = bfhi(p0.w);
    f[8] = bflo(p1.x); f[9] = bfhi(p1.x); f[10] = bflo(p1.y); f[11] = bfhi(p1.y);
    f[12] = bflo(p1.z); f[13] = bfhi(p1.z); f[14] = bflo(p1.w); f[15] = bfhi(p1.w);
    float sum = 0.f, sq = 0.f;
    #pragma unroll
    for (int i = 0; i < 16; i++) { sum += f[i]; sq += f[i] * f[i]; }
    blk_sum2(sum, sq, s8);
    float mu = sum * (1.f / 4096.f);
    float var = sq * (1.f / 4096.f) - mu * mu;
    float rs = rsqrtf(var + EPS);
    const float4* g4 = (const float4*)g;
    const float4* b4 = (const float4*)b;
    float amax = 0.f;
    #pragma unroll
    for (int i = 0; i < 4; i++) {
        float4 gg = g4[t * 4 + i];
        float4 bb = b4[t * 4 + i];
        float y0 = (f[i * 4 + 0] - mu) * rs * gg.x + bb.x;
        float y1 = (f[i * 4 + 1] - mu) * rs * gg.y + bb.y;
        float y2 = (f[i * 4 + 2] - mu) * rs * gg.z + bb.z;
        float y3 = (f[i * 4 + 3] - mu) * rs * gg.w + bb.w;
        f[i * 4 + 0] = y0 / (1.f + expf(-y0));
        f[i * 4 + 1] = y1 / (1.f + expf(-y1));
        f[i * 4 + 2] = y2 / (1.f + expf(-y2));
        f[i * 4 + 3] = y3 / (1.f + expf(-y3));
    }
    #pragma unroll
    for (int i = 0; i < 16; i++) amax = fmaxf(amax, fabsf(f[i]));
    amax = blk_max(amax, s8);
    amax = fmaxf(amax, EPS);
    float scale = 127.f / amax;
    if (t == 0) inv_s[row] = amax / 127.f;
    int4 o;
    o.x = pack4(rintf(f[0] * scale), rintf(f[1] * scale), rintf(f[2] * scale), rintf(f[3] * scale), -128.f, 127.f);
    o.y = pack4(rintf(f[4] * scale), rintf(f[5] * scale), rintf(f[6] * scale), rintf(f[7] * scale), -128.f, 127.f);
    o.z = pack4(rintf(f[8] * scale), rintf(f[9] * scale), rintf(f[10] * scale), rintf(f[11] * scale), -128.f, 127.f);
    o.w = pack4(rintf(f[12] * scale), rintf(f[13] * scale), rintf(f[14] * scale), rintf(f[15] * scale), -128.f, 127.f);
    ((int4*)((char*)q + (size_t)row * 4096))[t] = o;
}

// ---------------- async global->LDS helper ----------------
__device__ __forceinline__ void load_lds16(const void* g, void* l) {
    __builtin_amdgcn_global_load_lds((__attribute__((address_space(1))) void*)(g),
                                     (__attribute__((address_space(3))) void*)(l), 16, 0, 0);
}

// ---------------- 128x128 i8 MFMA GEMM (kept for GEMM3, N=2048) ----------------
template <int MODE>  // 0: write bf16 h; 1: final sigmoid epilogue into d_out
__global__ __launch_bounds__(256, 2) void gemm_i8_kernel(
    const char* __restrict__ A, const char* __restrict__ B,
    const float* __restrict__ inv_s, const float* __restrict__ wsum, float invWN,
    int K, void* __restrict__ outp) {
    __shared__ __align__(16) char lA[128 * 128];
    __shared__ __align__(16) char lB[128 * 128];
    const int t = threadIdx.x;
    const int lane = t & 63;
    const int wave = t >> 6;
    const int bm = blockIdx.y * 128, bn = blockIdx.x * 128;
    const int wr = (wave >> 1) * 64, wc = (wave & 1) * 64;

    int32x4 acc[4][4] = {};

    const int r0 = t >> 3;
    const int c0 = (t & 7) * 16;
    const int gcol = c0 ^ (16 * (r0 & 7));
    const char* gA = A + (size_t)(bm + r0) * K + gcol;
    const char* gB = B + (size_t)(bn + r0) * K + gcol;
    char* sA = lA + t * 16;
    char* sB = lB + t * 16;

    const int fr = lane & 15;
    const int fq = lane >> 4;
    const int swz = 16 * (fr & 7);

    for (int k0 = 0; k0 < K; k0 += 128) {
        #pragma unroll
        for (int j = 0; j < 4; j++)
            load_lds16(gA + (size_t)(j * 32) * K + k0, sA + j * 4096);
        #pragma unroll
        for (int j = 0; j < 4; j++)
            load_lds16(gB + (size_t)(j * 32) * K + k0, sB + j * 4096);
        __syncthreads();

        #pragma unroll
        for (int ks = 0; ks < 2; ks++) {
            const int col = (ks * 64 + fq * 16) ^ swz;
            int32x4 af[4], bf[4];
            #pragma unroll
            for (int mt = 0; mt < 4; mt++)
                af[mt] = *(const int32x4*)(lA + (wr + mt * 16 + fr) * 128 + col);
            #pragma unroll
            for (int nt = 0; nt < 4; nt++)
                bf[nt] = *(const int32x4*)(lB + (wc + nt * 16 + fr) * 128 + col);
            #pragma unroll
            for (int mt = 0; mt < 4; mt++) {
                #pragma unroll
                for (int nt = 0; nt < 4; nt++) {
                    acc[mt][nt] = __builtin_amdgcn_mfma_i32_16x16x64_i8(af[mt], bf[nt],
                                                                        acc[mt][nt], 0, 0, 0);
                }
            }
        }
        __syncthreads();
    }

    const float wmean = fmaxf(wsum[0] * invWN, EPS);
    #pragma unroll
    for (int mt = 0; mt < 4; mt++) {
        #pragma unroll
        for (int rg = 0; rg < 4; rg++) {
            int gr = bm + wr + mt * 16 + fq * 4 + rg;
            float rowscale = inv_s[gr] * wmean;
            #pragma unroll
            for (int nt = 0; nt < 4; nt++) {
                int gc = bn + wc + nt * 16 + fr;
                float v = (float)acc[mt][nt][rg] * rowscale;
                if (MODE == 0) {
                    ((__hip_bfloat16*)outp)[(size_t)gr * 4096 + gc] = __float2bfloat16(v);
                } else {
                    if (gc < 2000) {
                        float sg = 1.f / (1.f + expf(-v));
                        float* out = (float*)outp;
                        if (gc < 1000)
                            out[(size_t)gr * 1000 + gc] = sg * 999.f + 1.f;
                        else
                            out[(size_t)4096 * 1000 + (size_t)gr * 1000 + (gc - 1000)] =
                                sg * 100.f;
                    }
                }
            }
        }
    }
}

// ================= 256x256 8-phase i8 MFMA GEMM (T2+T3+T4+T5+T1) =================
// 512 threads = 8 waves (2M x 4N); per-wave 128x64 output = acc[8][4].
// BK = 128 bytes; K-tile split into 4 half-tiles along K: A-klo, B-klo, A-khi, B-khi
// (16 KB each = 2 x global_load_lds dwordx4). LDS [buf][kh][256][64] with chunk-XOR
// swizzle (chunk ^= (row>>1)&3) applied to BOTH the pre-swizzled global source and
// the ds_read address -> conflict-free ds_read_b128.
// Counted vmcnt(4) at tails of phases 1 & 3 only (never 0 in main loop): every
// staged half-tile has >=3 MFMA phases of latency cover before its wait.
template <int MH>
__device__ __forceinline__ void mfma_quad(int32x4 (&acc)[8][4], const int32x4 (&af)[4],
                                          const int32x4 (&bf)[4]) {
    #pragma unroll
    for (int i = 0; i < 4; i++) {
        #pragma unroll
        for (int j = 0; j < 4; j++) {
            acc[MH * 4 + i][j] =
                __builtin_amdgcn_mfma_i32_16x16x64_i8(af[i], bf[j], acc[MH * 4 + i][j], 0, 0, 0);
        }
    }
}

__global__ __launch_bounds__(512, 2) void gemm_i8_big(
    const char* __restrict__ A, const char* __restrict__ B,
    const float* __restrict__ inv_s, const float* __restrict__ wsum, float invWN,
    int K, __hip_bfloat16* __restrict__ outp) {
    __shared__ __align__(16) char lA[2][2][256][64];   // [buf][kh][row][64B] = 64 KB
    __shared__ __align__(16) char lB[2][2][256][64];   // 64 KB
    const int t = threadIdx.x;
    const int lane = t & 63;
    const int wave = t >> 6;

    // T1: bijective XCD swizzle (nwg = 256, divisible by 8)
    const int nwg = gridDim.x * gridDim.y;
    const int wg0 = blockIdx.y * gridDim.x + blockIdx.x;
    const int q8 = nwg >> 3;
    const int wg = (wg0 & 7) * q8 + (wg0 >> 3);
    const int bm = (wg / gridDim.x) * 256;
    const int bn = (wg % gridDim.x) * 256;

    const int wr = (wave >> 2) * 128;   // 2 M-waves
    const int wc = (wave & 3) * 64;     // 4 N-waves

    // fragment read addressing (lane = fq*16 + fr)
    const int fr = lane & 15;
    const int fq = lane >> 4;
    const int rchunk = (fq ^ ((fr >> 1) & 3)) * 16;    // read-side XOR unswizzle
    const char* aRd = &lA[0][0][0][0] + (wr + fr) * 64 + rchunk;
    const char* bRd = &lB[0][0][0][0] + (wc + fr) * 64 + rchunk;

    // staging addressing: thread t -> LDS row t>>2, chunk t&3 (linear dest),
    // global source chunk pre-swizzled by the same XOR
    const int srow = t >> 2;
    const int schunk = ((t & 3) ^ ((t >> 3) & 3)) * 16;
    const char* gA = A + (size_t)(bm + srow) * K + schunk;
    const char* gB = B + (size_t)(bn + srow) * K + schunk;
    char* sAd = &lA[0][0][0][0] + t * 16;
    char* sBd = &lB[0][0][0][0] + t * 16;

    int32x4 acc[8][4] = {};
    int32x4 af[4], bf[4];

    const int NT = K >> 7;

#define STAGE_A(bb, kh, kt) \
    load_lds16(gA + (size_t)(kt) * 128 + (kh) * 64, sAd + (bb) * 32768 + (kh) * 16384); \
    load_lds16(gA + (size_t)128 * K + (size_t)(kt) * 128 + (kh) * 64, \
               sAd + (bb) * 32768 + (kh) * 16384 + 8192);
#define STAGE_B(bb, kh, kt) \
    load_lds16(gB + (size_t)(kt) * 128 + (kh) * 64, sBd + (bb) * 32768 + (kh) * 16384); \
    load_lds16(gB + (size_t)128 * K + (size_t)(kt) * 128 + (kh) * 64, \
               sBd + (bb) * 32768 + (kh) * 16384 + 8192);
#define LD_AF(bb, ks, mh) { \
    const char* p_ = aRd + (bb) * 32768 + (ks) * 16384 + (mh) * 4096; \
    af[0] = *(const int32x4*)(p_); \
    af[1] = *(const int32x4*)(p_ + 1024); \
    af[2] = *(const int32x4*)(p_ + 2048); \
    af[3] = *(const int32x4*)(p_ + 3072); }
#define LD_BF(bb, ks) { \
    const char* p_ = bRd + (bb) * 32768 + (ks) * 16384; \
    bf[0] = *(const int32x4*)(p_); \
    bf[1] = *(const int32x4*)(p_ + 1024); \
    bf[2] = *(const int32x4*)(p_ + 2048); \
    bf[3] = *(const int32x4*)(p_ + 3072); }

    // prologue: stage tile 0 fully into buf 0; wait only for the klo halves
    STAGE_A(0, 0, 0); STAGE_B(0, 0, 0); STAGE_A(0, 1, 0); STAGE_B(0, 1, 0);
    asm volatile("s_waitcnt vmcnt(4)" ::: "memory");
    __builtin_amdgcn_s_barrier();

    for (int kt = 0; kt < NT - 1; ++kt) {
        const int b = kt & 1, nb = b ^ 1;
        // phase 0: ks=0, m-half 0; stage A-klo(kt+1)
        LD_BF(b, 0); LD_AF(b, 0, 0);
        STAGE_A(nb, 0, kt + 1);
        __builtin_amdgcn_s_barrier();
        asm volatile("s_waitcnt lgkmcnt(0)" ::: "memory");
        __builtin_amdgcn_s_setprio(1);
        mfma_quad<0>(acc, af, bf);
        __builtin_amdgcn_s_setprio(0);
        __builtin_amdgcn_s_barrier();
        // phase 1: ks=0, m-half 1; stage B-klo(kt+1); counted wait for khi(kt)
        LD_AF(b, 0, 1);
        STAGE_B(nb, 0, kt + 1);
        __builtin_amdgcn_s_barrier();
        asm volatile("s_waitcnt lgkmcnt(0)" ::: "memory");
        __builtin_amdgcn_s_setprio(1);
        mfma_quad<1>(acc, af, bf);
        __builtin_amdgcn_s_setprio(0);
        asm volatile("s_waitcnt vmcnt(4)" ::: "memory");
        __builtin_amdgcn_s_barrier();
        // phase 2: ks=1, m-half 0; stage A-khi(kt+1)
        LD_BF(b, 1); LD_AF(b, 1, 0);
        STAGE_A(nb, 1, kt + 1);
        __builtin_amdgcn_s_barrier();
        asm volatile("s_waitcnt lgkmcnt(0)" ::: "memory");
        __builtin_amdgcn_s_setprio(1);
        mfma_quad<0>(acc, af, bf);
        __builtin_amdgcn_s_setprio(0);
        __builtin_amdgcn_s_barrier();
        // phase 3: ks=1, m-half 1; stage B-khi(kt+1); counted wait for klo(kt+1)
        LD_AF(b, 1, 1);
        STAGE_B(nb, 1, kt + 1);
        __builtin_amdgcn_s_barrier();
        asm volatile("s_waitcnt lgkmcnt(0)" ::: "memory");
        __builtin_amdgcn_s_setprio(1);
        mfma_quad<1>(acc, af, bf);
        __builtin_amdgcn_s_setprio(0);
        asm volatile("s_waitcnt vmcnt(4)" ::: "memory");
        __builtin_amdgcn_s_barrier();
    }

    // epilogue tile NT-1 (no staging; one vmcnt(0) before the khi phases)
    {
        const int b = (NT - 1) & 1;
        LD_BF(b, 0); LD_AF(b, 0, 0);
        __builtin_amdgcn_s_barrier();
        asm volatile("s_waitcnt lgkmcnt(0)" ::: "memory");
        __builtin_amdgcn_s_setprio(1);
        mfma_quad<0>(acc, af, bf);
        __builtin_amdgcn_s_setprio(0);
        __builtin_amdgcn_s_barrier();
        LD_AF(b, 0, 1);
        __builtin_amdgcn_s_barrier();
        asm volatile("s_waitcnt lgkmcnt(0)" ::: "memory");
        __builtin_amdgcn_s_setprio(1);
        mfma_quad<1>(acc, af, bf);
        __builtin_amdgcn_s_setprio(0);
        asm volatile("s_waitcnt vmcnt(0)" ::: "memory");
        __builtin_amdgcn_s_barrier();
        LD_BF(b, 1); LD_AF(b, 1, 0);
        __builtin_amdgcn_s_barrier();
        asm volatile("s_waitcnt lgkmcnt(0)" ::: "memory");
        __builtin_amdgcn_s_setprio(1);
        mfma_quad<0>(acc, af, bf);
        __builtin_amdgcn_s_setprio(0);
        __builtin_amdgcn_s_barrier();
        LD_AF(b, 1, 1);
        asm volatile("s_waitcnt lgkmcnt(0)" ::: "memory");
        __builtin_amdgcn_s_setprio(1);
        mfma_quad<1>(acc, af, bf);
        __builtin_amdgcn_s_setprio(0);
    }
#undef STAGE_A
#undef STAGE_B
#undef LD_AF
#undef LD_BF

    const float wmean = fmaxf(wsum[0] * invWN, EPS);
    #pragma unroll
    for (int mt = 0; mt < 8; mt++) {
        #pragma unroll
        for (int rg = 0; rg < 4; rg++) {
            const int gr = bm + wr + mt * 16 + fq * 4 + rg;
            const float rowscale = inv_s[gr] * wmean;
            #pragma unroll
            for (int nt = 0; nt < 4; nt++) {
                const int gc = bn + wc + nt * 16 + fr;
                outp[(size_t)gr * 4096 + gc] =
                    __float2bfloat16((float)acc[mt][nt][rg] * rowscale);
            }
        }
    }
}

// ---------------- host launcher ----------------
extern "C" void kernel_launch(void* const* d_in, const int* in_sizes, int n_in,
                              void* d_out, int out_size, void* d_ws, size_t ws_size,
                              hipStream_t stream) {
    const float* x  = (const float*)d_in[0];
    const float* W0 = (const float*)d_in[1];
    const float* W1 = (const float*)d_in[2];
    const float* W2 = (const float*)d_in[3];
    const float* W3 = (const float*)d_in[4];
    const float* g0 = (const float*)d_in[5];
    const float* b0 = (const float*)d_in[6];
    const float* g1 = (const float*)d_in[7];
    const float* b1 = (const float*)d_in[8];
    const float* g2 = (const float*)d_in[9];
    const float* b2 = (const float*)d_in[10];
    float* out = (float*)d_out;

    char* ws = (char*)d_ws;
    size_t off = 0;
    auto alloc = [&](size_t bytes) -> char* {
        char* p = ws + off;
        off = (off + bytes + 255) & ~(size_t)255;
        return p;
    };
    float* part = (float*)alloc(256 * 16 * sizeof(float));
    float* sums = (float*)alloc(4 * sizeof(float));
    float* inv0 = (float*)alloc(4096 * 4);
    float* inv1 = (float*)alloc(4096 * 4);
    float* inv2 = (float*)alloc(4096 * 4);
    float* inv3 = (float*)alloc(4096 * 4);
    char* wq0 = alloc(4096ll * 1024);
    char* wq1 = alloc(4096ll * 4096);
    char* wq2 = alloc(4096ll * 4096);
    char* wq3 = alloc(2048ll * 4096);
    char* a0  = alloc(4096ll * 1024);
    char* a1  = alloc(4096ll * 4096);
    char* a2  = alloc(4096ll * 4096);
    char* h   = alloc(4096ll * 4096 * 2);
    char* a3 = a1;  // a1 dead after GEMM1; safe sequential reuse

    hipMemsetAsync(part, 0, 256 * 16 * sizeof(float), stream);

    absmean_all_kernel<<<11216, 256, 0, stream>>>(W0, W1, W2, W3, part);
    reduce_sums_kernel<<<1, 256, 0, stream>>>(part, sums);
    actquant_kernel<<<4096, 256, 0, stream>>>(x, (int*)a0, inv0);
    wquant_all_kernel<<<11264, 256, 0, stream>>>(W0, W1, W2, W3, (int*)wq0, (int*)wq1,
                                                 (int*)wq2, (int*)wq3, sums);

    gemm_i8_big<<<dim3(16, 16), 512, 0, stream>>>(a0, wq0, inv0, sums + 0,
                                                  1.f / 4194304.f, 1024,
                                                  (__hip_bfloat16*)h);
    ln_silu_quant_kernel<<<4096, 256, 0, stream>>>((const ushort*)h, g0, b0, (int*)a1, inv1);

    gemm_i8_big<<<dim3(16, 16), 512, 0, stream>>>(a1, wq1, inv1, sums + 1,
                                                  1.f / 16777216.f, 4096,
                                                  (__hip_bfloat16*)h);
    ln_silu_quant_kernel<<<4096, 256, 0, stream>>>((const ushort*)h, g1, b1, (int*)a2, inv2);

    gemm_i8_big<<<dim3(16, 16), 512, 0, stream>>>(a2, wq2, inv2, sums + 2,
                                                  1.f / 16777216.f, 4096,
                                                  (__hip_bfloat16*)h);
    ln_silu_quant_kernel<<<4096, 256, 0, stream>>>((const ushort*)h, g2, b2, (int*)a3, inv3);

    gemm_i8_kernel<1><<<dim3(16, 32), 256, 0, stream>>>(a3, wq3, inv3, sums + 3,
                                                        1.f / 8192000.f, 4096, out);
}

// Round 2
// 522.868 us; speedup vs baseline: 1.0364x; 1.0364x over previous
//
#include <hip/hip_runtime.h>
#include <hip/hip_bf16.h>
#include <cstdint>
#include <cstddef>

#define EPS 1e-5f

typedef __attribute__((ext_vector_type(4))) int int32x4;

// ---------------- block reduction helpers (256 threads = 4 waves) ----------------
__device__ __forceinline__ float blk_sum(float v, float* s4) {
    #pragma unroll
    for (int o = 32; o; o >>= 1) v += __shfl_down(v, o, 64);
    if ((threadIdx.x & 63) == 0) s4[threadIdx.x >> 6] = v;
    __syncthreads();
    v = s4[0] + s4[1] + s4[2] + s4[3];
    __syncthreads();
    return v;
}

__device__ __forceinline__ void blk_sum2(float& a, float& b, float* s8) {
    #pragma unroll
    for (int o = 32; o; o >>= 1) {
        a += __shfl_down(a, o, 64);
        b += __shfl_down(b, o, 64);
    }
    if ((threadIdx.x & 63) == 0) {
        s8[threadIdx.x >> 6] = a;
        s8[4 + (threadIdx.x >> 6)] = b;
    }
    __syncthreads();
    a = s8[0] + s8[1] + s8[2] + s8[3];
    b = s8[4] + s8[5] + s8[6] + s8[7];
    __syncthreads();
}

__device__ __forceinline__ float blk_max(float v, float* s4) {
    #pragma unroll
    for (int o = 32; o; o >>= 1) v = fmaxf(v, __shfl_down(v, o, 64));
    if ((threadIdx.x & 63) == 0) s4[threadIdx.x >> 6] = v;
    __syncthreads();
    v = fmaxf(fmaxf(s4[0], s4[1]), fmaxf(s4[2], s4[3]));
    __syncthreads();
    return v;
}

__device__ __forceinline__ int pack4(float a, float b, float c, float d, float lo, float hi) {
    int x0 = (int)fminf(fmaxf(a, lo), hi);
    int x1 = (int)fminf(fmaxf(b, lo), hi);
    int x2 = (int)fminf(fmaxf(c, lo), hi);
    int x3 = (int)fminf(fmaxf(d, lo), hi);
    return (x0 & 255) | ((x1 & 255) << 8) | ((x2 & 255) << 16) | ((x3 & 255) << 24);
}

__device__ __forceinline__ float bflo(unsigned u) { return __uint_as_float(u << 16); }
__device__ __forceinline__ float bfhi(unsigned u) { return __uint_as_float(u & 0xffff0000u); }

// ---------------- fused absmean over all 4 weights (1 launch) --------------------------
__global__ __launch_bounds__(256) void absmean_all_kernel(
    const float* __restrict__ W0, const float* __restrict__ W1,
    const float* __restrict__ W2, const float* __restrict__ W3,
    float* __restrict__ part) {
    __shared__ float s4[4];
    const float* w; int sidx; unsigned rel;
    unsigned bx = blockIdx.x;
    if (bx < 1024)      { w = W0; sidx = 0; rel = bx; }
    else if (bx < 5120) { w = W1; sidx = 1; rel = bx - 1024; }
    else if (bx < 9216) { w = W2; sidx = 2; rel = bx - 5120; }
    else                { w = W3; sidx = 3; rel = bx - 9216; }
    const float4* p = (const float4*)w + (size_t)rel * 1024 + threadIdx.x;
    float4 v0 = p[0], v1 = p[256], v2 = p[512], v3 = p[768];
    float s = fabsf(v0.x) + fabsf(v0.y) + fabsf(v0.z) + fabsf(v0.w)
            + fabsf(v1.x) + fabsf(v1.y) + fabsf(v1.z) + fabsf(v1.w)
            + fabsf(v2.x) + fabsf(v2.y) + fabsf(v2.z) + fabsf(v2.w)
            + fabsf(v3.x) + fabsf(v3.y) + fabsf(v3.z) + fabsf(v3.w);
    s = blk_sum(s, s4);
    if (threadIdx.x == 0) atomicAdd(&part[(sidx * 64 + (rel & 63)) * 16], s);
}

// ---------------- reduce 256 spread slots -> sums[4] ------
__global__ __launch_bounds__(256) void reduce_sums_kernel(const float* __restrict__ part,
                                                          float* __restrict__ sums) {
    int w = threadIdx.x >> 6, l = threadIdx.x & 63;
    float v = part[(w * 64 + l) * 16];
    #pragma unroll
    for (int o = 32; o; o >>= 1) v += __shfl_down(v, o, 64);
    if (l == 0) sums[w] = v;
}

// ---------------- fused ternary quantization for all 4 weights + W3 pad ----------------
__global__ __launch_bounds__(256) void wquant_all_kernel(
    const float* __restrict__ W0, const float* __restrict__ W1,
    const float* __restrict__ W2, const float* __restrict__ W3,
    int* __restrict__ q0, int* __restrict__ q1, int* __restrict__ q2, int* __restrict__ q3,
    const float* __restrict__ sums) {
    const float* w; int* q; int sidx; unsigned rel; float invN; bool pad = false;
    unsigned bx = blockIdx.x;
    if (bx < 1024)      { w = W0; q = q0; sidx = 0; rel = bx;        invN = 1.f / 4194304.f; }
    else if (bx < 5120) { w = W1; q = q1; sidx = 1; rel = bx - 1024; invN = 1.f / 16777216.f; }
    else if (bx < 9216) { w = W2; q = q2; sidx = 2; rel = bx - 5120; invN = 1.f / 16777216.f; }
    else                { w = W3; q = q3; sidx = 3; rel = bx - 9216; invN = 1.f / 8192000.f;
                          pad = (rel >= 2000); }
    int4 o = {0, 0, 0, 0};
    if (!pad) {
        float mean = fmaxf(sums[sidx] * invN, EPS);
        float scale = 1.f / mean;
        const float4* p = (const float4*)w + (size_t)rel * 1024 + threadIdx.x * 4;
        float4 v0 = p[0], v1 = p[1], v2 = p[2], v3 = p[3];
        o.x = pack4(rintf(v0.x * scale), rintf(v0.y * scale), rintf(v0.z * scale), rintf(v0.w * scale), -1.f, 1.f);
        o.y = pack4(rintf(v1.x * scale), rintf(v1.y * scale), rintf(v1.z * scale), rintf(v1.w * scale), -1.f, 1.f);
        o.z = pack4(rintf(v2.x * scale), rintf(v2.y * scale), rintf(v2.z * scale), rintf(v2.w * scale), -1.f, 1.f);
        o.w = pack4(rintf(v3.x * scale), rintf(v3.y * scale), rintf(v3.z * scale), rintf(v3.w * scale), -1.f, 1.f);
    }
    ((int4*)q)[(size_t)rel * 256 + threadIdx.x] = o;
}

// ---------------- input activation quantization (D = 1024) ----------------
__global__ __launch_bounds__(256) void actquant_kernel(const float* __restrict__ x,
                                                       int* __restrict__ q,
                                                       float* __restrict__ inv_s) {
    __shared__ float s4[4];
    int row = blockIdx.x;
    const float4* xr = (const float4*)(x + (size_t)row * 1024);
    float4 v = xr[threadIdx.x];
    float m = fmaxf(fmaxf(fabsf(v.x), fabsf(v.y)), fmaxf(fabsf(v.z), fabsf(v.w)));
    m = blk_max(m, s4);
    m = fmaxf(m, EPS);
    float scale = 127.f / m;
    if (threadIdx.x == 0) inv_s[row] = m / 127.f;
    q[(size_t)row * 256 + threadIdx.x] =
        pack4(rintf(v.x * scale), rintf(v.y * scale),
              rintf(v.z * scale), rintf(v.w * scale), -128.f, 127.f);
}

// ---------------- fused LayerNorm + SiLU + act quant, bf16 input (H = 4096) ------------
__global__ __launch_bounds__(256) void ln_silu_quant_kernel(const ushort* __restrict__ h,
                                                            const float* __restrict__ g,
                                                            const float* __restrict__ b,
                                                            int* __restrict__ q,
                                                            float* __restrict__ inv_s) {
    __shared__ float s8[8];
    int row = blockIdx.x;
    int t = threadIdx.x;
    const uint4* hr = (const uint4*)(h + (size_t)row * 4096);
    uint4 p0 = hr[t * 2], p1 = hr[t * 2 + 1];
    float f[16];
    f[0] = bflo(p0.x); f[1] = bfhi(p0.x); f[2] = bflo(p0.y); f[3] = bfhi(p0.y);
    f[4] = bflo(p0.z); f[5] = bfhi(p0.z); f[6] = bflo(p0.w); f[7] = bfhi(p0.w);
    f[8] = bflo(p1.x); f[9] = bfhi(p1.x); f[10] = bflo(p1.y); f[11] = bfhi(p1.y);
    f[12] = bflo(p1.z); f[13] = bfhi(p1.z); f[14] = bflo(p1.w); f[15] = bfhi(p1.w);
    float sum = 0.f, sq = 0.f;
    #pragma unroll
    for (int i = 0; i < 16; i++) { sum += f[i]; sq += f[i] * f[i]; }
    blk_sum2(sum, sq, s8);
    float mu = sum * (1.f / 4096.f);
    float var = sq * (1.f / 4096.f) - mu * mu;
    float rs = rsqrtf(var + EPS);
    const float4* g4 = (const float4*)g;
    const float4* b4 = (const float4*)b;
    float amax = 0.f;
    #pragma unroll
    for (int i = 0; i < 4; i++) {
        float4 gg = g4[t * 4 + i];
        float4 bb = b4[t * 4 + i];
        float y0 = (f[i * 4 + 0] - mu) * rs * gg.x + bb.x;
        float y1 = (f[i * 4 + 1] - mu) * rs * gg.y + bb.y;
        float y2 = (f[i * 4 + 2] - mu) * rs * gg.z + bb.z;
        float y3 = (f[i * 4 + 3] - mu) * rs * gg.w + bb.w;
        f[i * 4 + 0] = y0 / (1.f + expf(-y0));
        f[i * 4 + 1] = y1 / (1.f + expf(-y1));
        f[i * 4 + 2] = y2 / (1.f + expf(-y2));
        f[i * 4 + 3] = y3 / (1.f + expf(-y3));
    }
    #pragma unroll
    for (int i = 0; i < 16; i++) amax = fmaxf(amax, fabsf(f[i]));
    amax = blk_max(amax, s8);
    amax = fmaxf(amax, EPS);
    float scale = 127.f / amax;
    if (t == 0) inv_s[row] = amax / 127.f;
    int4 o;
    o.x = pack4(rintf(f[0] * scale), rintf(f[1] * scale), rintf(f[2] * scale), rintf(f[3] * scale), -128.f, 127.f);
    o.y = pack4(rintf(f[4] * scale), rintf(f[5] * scale), rintf(f[6] * scale), rintf(f[7] * scale), -128.f, 127.f);
    o.z = pack4(rintf(f[8] * scale), rintf(f[9] * scale), rintf(f[10] * scale), rintf(f[11] * scale), -128.f, 127.f);
    o.w = pack4(rintf(f[12] * scale), rintf(f[13] * scale), rintf(f[14] * scale), rintf(f[15] * scale), -128.f, 127.f);
    ((int4*)((char*)q + (size_t)row * 4096))[t] = o;
}

// ---------------- async global->LDS helper ----------------
__device__ __forceinline__ void load_lds16(const void* g, void* l) {
    __builtin_amdgcn_global_load_lds((__attribute__((address_space(1))) void*)(g),
                                     (__attribute__((address_space(3))) void*)(l), 16, 0, 0);
}

// ---------------- 128x128 i8 MFMA GEMM (kept for GEMM3, N=2048) ----------------
template <int MODE>  // 1: final sigmoid epilogue into d_out
__global__ __launch_bounds__(256, 2) void gemm_i8_kernel(
    const char* __restrict__ A, const char* __restrict__ B,
    const float* __restrict__ inv_s, const float* __restrict__ wsum, float invWN,
    int K, void* __restrict__ outp) {
    __shared__ __align__(16) char lA[128 * 128];
    __shared__ __align__(16) char lB[128 * 128];
    const int t = threadIdx.x;
    const int lane = t & 63;
    const int wave = t >> 6;
    const int bm = blockIdx.y * 128, bn = blockIdx.x * 128;
    const int wr = (wave >> 1) * 64, wc = (wave & 1) * 64;

    int32x4 acc[4][4] = {};

    const int r0 = t >> 3;
    const int c0 = (t & 7) * 16;
    const int gcol = c0 ^ (16 * (r0 & 7));
    const char* gA = A + (size_t)(bm + r0) * K + gcol;
    const char* gB = B + (size_t)(bn + r0) * K + gcol;
    char* sA = lA + t * 16;
    char* sB = lB + t * 16;

    const int fr = lane & 15;
    const int fq = lane >> 4;
    const int swz = 16 * (fr & 7);

    for (int k0 = 0; k0 < K; k0 += 128) {
        #pragma unroll
        for (int j = 0; j < 4; j++)
            load_lds16(gA + (size_t)(j * 32) * K + k0, sA + j * 4096);
        #pragma unroll
        for (int j = 0; j < 4; j++)
            load_lds16(gB + (size_t)(j * 32) * K + k0, sB + j * 4096);
        __syncthreads();

        #pragma unroll
        for (int ks = 0; ks < 2; ks++) {
            const int col = (ks * 64 + fq * 16) ^ swz;
            int32x4 af[4], bf[4];
            #pragma unroll
            for (int mt = 0; mt < 4; mt++)
                af[mt] = *(const int32x4*)(lA + (wr + mt * 16 + fr) * 128 + col);
            #pragma unroll
            for (int nt = 0; nt < 4; nt++)
                bf[nt] = *(const int32x4*)(lB + (wc + nt * 16 + fr) * 128 + col);
            #pragma unroll
            for (int mt = 0; mt < 4; mt++) {
                #pragma unroll
                for (int nt = 0; nt < 4; nt++) {
                    acc[mt][nt] = __builtin_amdgcn_mfma_i32_16x16x64_i8(af[mt], bf[nt],
                                                                        acc[mt][nt], 0, 0, 0);
                }
            }
        }
        __syncthreads();
    }

    const float wmean = fmaxf(wsum[0] * invWN, EPS);
    #pragma unroll
    for (int mt = 0; mt < 4; mt++) {
        #pragma unroll
        for (int rg = 0; rg < 4; rg++) {
            int gr = bm + wr + mt * 16 + fq * 4 + rg;
            float rowscale = inv_s[gr] * wmean;
            #pragma unroll
            for (int nt = 0; nt < 4; nt++) {
                int gc = bn + wc + nt * 16 + fr;
                float v = (float)acc[mt][nt][rg] * rowscale;
                if (MODE == 0) {
                    ((__hip_bfloat16*)outp)[(size_t)gr * 4096 + gc] = __float2bfloat16(v);
                } else {
                    if (gc < 2000) {
                        float sg = 1.f / (1.f + expf(-v));
                        float* out = (float*)outp;
                        if (gc < 1000)
                            out[(size_t)gr * 1000 + gc] = sg * 999.f + 1.f;
                        else
                            out[(size_t)4096 * 1000 + (size_t)gr * 1000 + (gc - 1000)] =
                                sg * 100.f;
                    }
                }
            }
        }
    }
}

// ================= 256x256 pipelined i8 GEMM: BK=64B, 4 LDS buffers =================
// 512 threads = 8 waves (2M x 4N); per-wave 128x64 output = acc[8][4].
// 2 phases per K-tile (mh0, mh1), 16 MFMA each. Fragment ds_reads are issued ONE
// PHASE AHEAD into alternate register sets (afX/afY per phase, bfX/bfY per tile)
// and awaited with COUNTED lgkmcnt(4)/lgkmcnt(8), so LDS service hides under MFMA.
// Staging runs 3 tiles ahead (A at phase0, B at phase1 -> 2 loads/wave/phase);
// vmcnt(6) once per tile publishes tile kt+1 with 3-4 phases of latency cover.
// One s_barrier per phase. All register indices static (4-tile unrolled body).
// Linear [256][64] LDS layout: read bank-quad = (4*fr+fq)%8 -> uniform, conflict-free.
template <int MH>
__device__ __forceinline__ void mfma_quad(int32x4 (&acc)[8][4], const int32x4 (&af)[4],
                                          const int32x4 (&bf)[4]) {
    #pragma unroll
    for (int i = 0; i < 4; i++) {
        #pragma unroll
        for (int j = 0; j < 4; j++) {
            acc[MH * 4 + i][j] =
                __builtin_amdgcn_mfma_i32_16x16x64_i8(af[i], bf[j], acc[MH * 4 + i][j], 0, 0, 0);
        }
    }
}

__global__ __launch_bounds__(512, 2) void gemm_i8_pipe(
    const char* __restrict__ A, const char* __restrict__ B,
    const float* __restrict__ inv_s, const float* __restrict__ wsum, float invWN,
    int K, __hip_bfloat16* __restrict__ outp) {
    __shared__ __align__(16) char lA[4][256][64];   // 64 KB (4 buffers)
    __shared__ __align__(16) char lB[4][256][64];   // 64 KB
    const int t = threadIdx.x;
    const int lane = t & 63;
    const int wave = t >> 6;

    // T1: bijective XCD swizzle (nwg = 256, divisible by 8)
    const int nwg = gridDim.x * gridDim.y;
    const int wg0 = blockIdx.y * gridDim.x + blockIdx.x;
    const int q8 = nwg >> 3;
    const int wg = (wg0 & 7) * q8 + (wg0 >> 3);
    const int bm = (wg / gridDim.x) * 256;
    const int bn = (wg % gridDim.x) * 256;

    const int wr = (wave >> 2) * 128;   // 2 M-waves
    const int wc = (wave & 3) * 64;     // 4 N-waves
    const int fr = lane & 15;
    const int fq = lane >> 4;

    // staging: thread t -> row t>>2, 16B chunk t&3 (linear both sides)
    const int srow = t >> 2;
    const char* gA = A + (size_t)(bm + srow) * K + (t & 3) * 16;
    const char* gB = B + (size_t)(bn + srow) * K + (t & 3) * 16;
    char* sAd = &lA[0][0][0] + t * 16;
    char* sBd = &lB[0][0][0] + t * 16;

    // fragment read bases: row = wr|wc + (mh*64) + mt*16 + fr, chunk = fq
    const char* aRd = &lA[0][0][0] + (wr + fr) * 64 + fq * 16;
    const char* bRd = &lB[0][0][0] + (wc + fr) * 64 + fq * 16;

    int32x4 acc[8][4] = {};
    int32x4 afX[4], afY[4], bfX[4], bfY[4];
    const int NT = K >> 6;   // BK = 64 bytes

#define STAGE_A(buf, kt) { \
    load_lds16(gA + (size_t)(kt) * 64, sAd + (buf) * 16384); \
    load_lds16(gA + (size_t)128 * K + (size_t)(kt) * 64, sAd + (buf) * 16384 + 8192); }
#define STAGE_B(buf, kt) { \
    load_lds16(gB + (size_t)(kt) * 64, sBd + (buf) * 16384); \
    load_lds16(gB + (size_t)128 * K + (size_t)(kt) * 64, sBd + (buf) * 16384 + 8192); }
#define LD_AF(dst, buf, mh) { \
    const char* p_ = aRd + (buf) * 16384 + (mh) * 4096; \
    dst[0] = *(const int32x4*)(p_); \
    dst[1] = *(const int32x4*)(p_ + 1024); \
    dst[2] = *(const int32x4*)(p_ + 2048); \
    dst[3] = *(const int32x4*)(p_ + 3072); }
#define LD_BF(dst, buf) { \
    const char* p_ = bRd + (buf) * 16384; \
    dst[0] = *(const int32x4*)(p_); \
    dst[1] = *(const int32x4*)(p_ + 1024); \
    dst[2] = *(const int32x4*)(p_ + 2048); \
    dst[3] = *(const int32x4*)(p_ + 3072); }
#define WAITL(n) { asm volatile("s_waitcnt lgkmcnt(" #n ")" ::: "memory"); \
                   __builtin_amdgcn_sched_barrier(0); }
#define WAITV(n) { asm volatile("s_waitcnt vmcnt(" #n ")" ::: "memory"); \
                   __builtin_amdgcn_sched_barrier(0); }
#define BAR() { __builtin_amdgcn_s_barrier(); __builtin_amdgcn_sched_barrier(0); }
#define MF0(afc, bfc) { __builtin_amdgcn_s_setprio(1); mfma_quad<0>(acc, afc, bfc); \
                        __builtin_amdgcn_s_setprio(0); }
#define MF1(afc, bfc) { __builtin_amdgcn_s_setprio(1); mfma_quad<1>(acc, afc, bfc); \
                        __builtin_amdgcn_s_setprio(0); }

    // prologue: stage tiles 0,1,2 into bufs 0,1,2; publish tile 0; issue tile-0 p0 reads
    STAGE_A(0, 0); STAGE_B(0, 0);
    STAGE_A(1, 1); STAGE_B(1, 1);
    STAGE_A(2, 2); STAGE_B(2, 2);
    WAITV(8);
    BAR();
    LD_BF(bfX, 0); LD_AF(afX, 0, 0);   // 8 outstanding lgkm into the loop

    // main loop: 4 tiles per iteration (bufs 0..3 static); consumes tiles 0..NT-5
    for (int kt = 0; kt <= NT - 8; kt += 4) {
        // tile kt+0: buf0, bfX
        STAGE_A(3, kt + 3); LD_AF(afY, 0, 1); WAITL(4); MF0(afX, bfX); WAITV(6); BAR();
        STAGE_B(3, kt + 3); LD_BF(bfY, 1); LD_AF(afX, 1, 0); WAITL(8); MF1(afY, bfX); BAR();
        // tile kt+1: buf1, bfY
        STAGE_A(0, kt + 4); LD_AF(afY, 1, 1); WAITL(4); MF0(afX, bfY); WAITV(6); BAR();
        STAGE_B(0, kt + 4); LD_BF(bfX, 2); LD_AF(afX, 2, 0); WAITL(8); MF1(afY, bfY); BAR();
        // tile kt+2: buf2, bfX
        STAGE_A(1, kt + 5); LD_AF(afY, 2, 1); WAITL(4); MF0(afX, bfX); WAITV(6); BAR();
        STAGE_B(1, kt + 5); LD_BF(bfY, 3); LD_AF(afX, 3, 0); WAITL(8); MF1(afY, bfX); BAR();
        // tile kt+3: buf3, bfY
        STAGE_A(2, kt + 6); LD_AF(afY, 3, 1); WAITL(4); MF0(afX, bfY); WAITV(6); BAR();
        STAGE_B(2, kt + 6); LD_BF(bfX, 0); LD_AF(afX, 0, 0); WAITL(8); MF1(afY, bfY); BAR();
    }

    // epilogue: tiles NT-4..NT-1 (bufs 0..3; NT % 4 == 0 so parity matches)
    // tile NT-4: buf0, bfX (stages the final tile NT-1 into buf3)
    STAGE_A(3, NT - 1); LD_AF(afY, 0, 1); WAITL(4); MF0(afX, bfX); WAITV(6); BAR();
    STAGE_B(3, NT - 1); LD_BF(bfY, 1); LD_AF(afX, 1, 0); WAITL(8); MF1(afY, bfX); BAR();
    // tile NT-3: buf1, bfY
    LD_AF(afY, 1, 1); WAITL(4); MF0(afX, bfY); WAITV(4); BAR();
    LD_BF(bfX, 2); LD_AF(afX, 2, 0); WAITL(8); MF1(afY, bfY); BAR();
    // tile NT-2: buf2, bfX
    LD_AF(afY, 2, 1); WAITL(4); MF0(afX, bfX); WAITV(0); BAR();
    LD_BF(bfY, 3); LD_AF(afX, 3, 0); WAITL(8); MF1(afY, bfX); BAR();
    // tile NT-1: buf3, bfY
    LD_AF(afY, 3, 1); WAITL(4); MF0(afX, bfY); BAR();
    WAITL(0); MF1(afY, bfY);

#undef STAGE_A
#undef STAGE_B
#undef LD_AF
#undef LD_BF
#undef WAITL
#undef WAITV
#undef BAR
#undef MF0
#undef MF1

    const float wmean = fmaxf(wsum[0] * invWN, EPS);
    #pragma unroll
    for (int mt = 0; mt < 8; mt++) {
        #pragma unroll
        for (int rg = 0; rg < 4; rg++) {
            const int gr = bm + wr + mt * 16 + fq * 4 + rg;
            const float rowscale = inv_s[gr] * wmean;
            #pragma unroll
            for (int nt = 0; nt < 4; nt++) {
                const int gc = bn + wc + nt * 16 + fr;
                outp[(size_t)gr * 4096 + gc] =
                    __float2bfloat16((float)acc[mt][nt][rg] * rowscale);
            }
        }
    }
}

// ---------------- host launcher ----------------
extern "C" void kernel_launch(void* const* d_in, const int* in_sizes, int n_in,
                              void* d_out, int out_size, void* d_ws, size_t ws_size,
                              hipStream_t stream) {
    const float* x  = (const float*)d_in[0];
    const float* W0 = (const float*)d_in[1];
    const float* W1 = (const float*)d_in[2];
    const float* W2 = (const float*)d_in[3];
    const float* W3 = (const float*)d_in[4];
    const float* g0 = (const float*)d_in[5];
    const float* b0 = (const float*)d_in[6];
    const float* g1 = (const float*)d_in[7];
    const float* b1 = (const float*)d_in[8];
    const float* g2 = (const float*)d_in[9];
    const float* b2 = (const float*)d_in[10];
    float* out = (float*)d_out;

    char* ws = (char*)d_ws;
    size_t off = 0;
    auto alloc = [&](size_t bytes) -> char* {
        char* p = ws + off;
        off = (off + bytes + 255) & ~(size_t)255;
        return p;
    };
    float* part = (float*)alloc(256 * 16 * sizeof(float));
    float* sums = (float*)alloc(4 * sizeof(float));
    float* inv0 = (float*)alloc(4096 * 4);
    float* inv1 = (float*)alloc(4096 * 4);
    float* inv2 = (float*)alloc(4096 * 4);
    float* inv3 = (float*)alloc(4096 * 4);
    char* wq0 = alloc(4096ll * 1024);
    char* wq1 = alloc(4096ll * 4096);
    char* wq2 = alloc(4096ll * 4096);
    char* wq3 = alloc(2048ll * 4096);
    char* a0  = alloc(4096ll * 1024);
    char* a1  = alloc(4096ll * 4096);
    char* a2  = alloc(4096ll * 4096);
    char* h   = alloc(4096ll * 4096 * 2);
    char* a3 = a1;  // a1 dead after GEMM1; safe sequential reuse

    hipMemsetAsync(part, 0, 256 * 16 * sizeof(float), stream);

    absmean_all_kernel<<<11216, 256, 0, stream>>>(W0, W1, W2, W3, part);
    reduce_sums_kernel<<<1, 256, 0, stream>>>(part, sums);
    actquant_kernel<<<4096, 256, 0, stream>>>(x, (int*)a0, inv0);
    wquant_all_kernel<<<11264, 256, 0, stream>>>(W0, W1, W2, W3, (int*)wq0, (int*)wq1,
                                                 (int*)wq2, (int*)wq3, sums);

    gemm_i8_pipe<<<dim3(16, 16), 512, 0, stream>>>(a0, wq0, inv0, sums + 0,
                                                   1.f / 4194304.f, 1024,
                                                   (__hip_bfloat16*)h);
    ln_silu_quant_kernel<<<4096, 256, 0, stream>>>((const ushort*)h, g0, b0, (int*)a1, inv1);

    gemm_i8_pipe<<<dim3(16, 16), 512, 0, stream>>>(a1, wq1, inv1, sums + 1,
                                                   1.f / 16777216.f, 4096,
                                                   (__hip_bfloat16*)h);
    ln_silu_quant_kernel<<<4096, 256, 0, stream>>>((const ushort*)h, g1, b1, (int*)a2, inv2);

    gemm_i8_pipe<<<dim3(16, 16), 512, 0, stream>>>(a2, wq2, inv2, sums + 2,
                                                   1.f / 16777216.f, 4096,
                                                   (__hip_bfloat16*)h);
    ln_silu_quant_kernel<<<4096, 256, 0, stream>>>((const ushort*)h, g2, b2, (int*)a3, inv3);

    gemm_i8_kernel<1><<<dim3(16, 32), 256, 0, stream>>>(a3, wq3, inv3, sums + 3,
                                                        1.f / 8192000.f, 4096, out);
}

// Round 3
// 515.365 us; speedup vs baseline: 1.0515x; 1.0146x over previous
//
#include <hip/hip_runtime.h>
#include <hip/hip_bf16.h>
#include <cstdint>
#include <cstddef>

#define EPS 1e-5f

typedef __attribute__((ext_vector_type(4))) int int32x4;

// ---------------- block reduction helpers (256 threads = 4 waves) ----------------
__device__ __forceinline__ float blk_sum(float v, float* s4) {
    #pragma unroll
    for (int o = 32; o; o >>= 1) v += __shfl_down(v, o, 64);
    if ((threadIdx.x & 63) == 0) s4[threadIdx.x >> 6] = v;
    __syncthreads();
    v = s4[0] + s4[1] + s4[2] + s4[3];
    __syncthreads();
    return v;
}

__device__ __forceinline__ void blk_sum2(float& a, float& b, float* s8) {
    #pragma unroll
    for (int o = 32; o; o >>= 1) {
        a += __shfl_down(a, o, 64);
        b += __shfl_down(b, o, 64);
    }
    if ((threadIdx.x & 63) == 0) {
        s8[threadIdx.x >> 6] = a;
        s8[4 + (threadIdx.x >> 6)] = b;
    }
    __syncthreads();
    a = s8[0] + s8[1] + s8[2] + s8[3];
    b = s8[4] + s8[5] + s8[6] + s8[7];
    __syncthreads();
}

__device__ __forceinline__ float blk_max(float v, float* s4) {
    #pragma unroll
    for (int o = 32; o; o >>= 1) v = fmaxf(v, __shfl_down(v, o, 64));
    if ((threadIdx.x & 63) == 0) s4[threadIdx.x >> 6] = v;
    __syncthreads();
    v = fmaxf(fmaxf(s4[0], s4[1]), fmaxf(s4[2], s4[3]));
    __syncthreads();
    return v;
}

__device__ __forceinline__ int pack4(float a, float b, float c, float d, float lo, float hi) {
    int x0 = (int)fminf(fmaxf(a, lo), hi);
    int x1 = (int)fminf(fmaxf(b, lo), hi);
    int x2 = (int)fminf(fmaxf(c, lo), hi);
    int x3 = (int)fminf(fmaxf(d, lo), hi);
    return (x0 & 255) | ((x1 & 255) << 8) | ((x2 & 255) << 16) | ((x3 & 255) << 24);
}

__device__ __forceinline__ float bflo(unsigned u) { return __uint_as_float(u << 16); }
__device__ __forceinline__ float bfhi(unsigned u) { return __uint_as_float(u & 0xffff0000u); }

// ---------------- fused absmean over all 4 weights (1 launch) --------------------------
__global__ __launch_bounds__(256) void absmean_all_kernel(
    const float* __restrict__ W0, const float* __restrict__ W1,
    const float* __restrict__ W2, const float* __restrict__ W3,
    float* __restrict__ part) {
    __shared__ float s4[4];
    const float* w; int sidx; unsigned rel;
    unsigned bx = blockIdx.x;
    if (bx < 1024)      { w = W0; sidx = 0; rel = bx; }
    else if (bx < 5120) { w = W1; sidx = 1; rel = bx - 1024; }
    else if (bx < 9216) { w = W2; sidx = 2; rel = bx - 5120; }
    else                { w = W3; sidx = 3; rel = bx - 9216; }
    const float4* p = (const float4*)w + (size_t)rel * 1024 + threadIdx.x;
    float4 v0 = p[0], v1 = p[256], v2 = p[512], v3 = p[768];
    float s = fabsf(v0.x) + fabsf(v0.y) + fabsf(v0.z) + fabsf(v0.w)
            + fabsf(v1.x) + fabsf(v1.y) + fabsf(v1.z) + fabsf(v1.w)
            + fabsf(v2.x) + fabsf(v2.y) + fabsf(v2.z) + fabsf(v2.w)
            + fabsf(v3.x) + fabsf(v3.y) + fabsf(v3.z) + fabsf(v3.w);
    s = blk_sum(s, s4);
    if (threadIdx.x == 0) atomicAdd(&part[(sidx * 64 + (rel & 63)) * 16], s);
}

// ---------------- reduce 256 spread slots -> sums[4] ------
__global__ __launch_bounds__(256) void reduce_sums_kernel(const float* __restrict__ part,
                                                          float* __restrict__ sums) {
    int w = threadIdx.x >> 6, l = threadIdx.x & 63;
    float v = part[(w * 64 + l) * 16];
    #pragma unroll
    for (int o = 32; o; o >>= 1) v += __shfl_down(v, o, 64);
    if (l == 0) sums[w] = v;
}

// ---------------- fused ternary quantization for all 4 weights + W3 pad ----------------
__global__ __launch_bounds__(256) void wquant_all_kernel(
    const float* __restrict__ W0, const float* __restrict__ W1,
    const float* __restrict__ W2, const float* __restrict__ W3,
    int* __restrict__ q0, int* __restrict__ q1, int* __restrict__ q2, int* __restrict__ q3,
    const float* __restrict__ sums) {
    const float* w; int* q; int sidx; unsigned rel; float invN; bool pad = false;
    unsigned bx = blockIdx.x;
    if (bx < 1024)      { w = W0; q = q0; sidx = 0; rel = bx;        invN = 1.f / 4194304.f; }
    else if (bx < 5120) { w = W1; q = q1; sidx = 1; rel = bx - 1024; invN = 1.f / 16777216.f; }
    else if (bx < 9216) { w = W2; q = q2; sidx = 2; rel = bx - 5120; invN = 1.f / 16777216.f; }
    else                { w = W3; q = q3; sidx = 3; rel = bx - 9216; invN = 1.f / 8192000.f;
                          pad = (rel >= 2000); }
    int4 o = {0, 0, 0, 0};
    if (!pad) {
        float mean = fmaxf(sums[sidx] * invN, EPS);
        float scale = 1.f / mean;
        const float4* p = (const float4*)w + (size_t)rel * 1024 + threadIdx.x * 4;
        float4 v0 = p[0], v1 = p[1], v2 = p[2], v3 = p[3];
        o.x = pack4(rintf(v0.x * scale), rintf(v0.y * scale), rintf(v0.z * scale), rintf(v0.w * scale), -1.f, 1.f);
        o.y = pack4(rintf(v1.x * scale), rintf(v1.y * scale), rintf(v1.z * scale), rintf(v1.w * scale), -1.f, 1.f);
        o.z = pack4(rintf(v2.x * scale), rintf(v2.y * scale), rintf(v2.z * scale), rintf(v2.w * scale), -1.f, 1.f);
        o.w = pack4(rintf(v3.x * scale), rintf(v3.y * scale), rintf(v3.z * scale), rintf(v3.w * scale), -1.f, 1.f);
    }
    ((int4*)q)[(size_t)rel * 256 + threadIdx.x] = o;
}

// ---------------- input activation quantization (D = 1024) ----------------
__global__ __launch_bounds__(256) void actquant_kernel(const float* __restrict__ x,
                                                       int* __restrict__ q,
                                                       float* __restrict__ inv_s) {
    __shared__ float s4[4];
    int row = blockIdx.x;
    const float4* xr = (const float4*)(x + (size_t)row * 1024);
    float4 v = xr[threadIdx.x];
    float m = fmaxf(fmaxf(fabsf(v.x), fabsf(v.y)), fmaxf(fabsf(v.z), fabsf(v.w)));
    m = blk_max(m, s4);
    m = fmaxf(m, EPS);
    float scale = 127.f / m;
    if (threadIdx.x == 0) inv_s[row] = m / 127.f;
    q[(size_t)row * 256 + threadIdx.x] =
        pack4(rintf(v.x * scale), rintf(v.y * scale),
              rintf(v.z * scale), rintf(v.w * scale), -128.f, 127.f);
}

// ---------------- fused LayerNorm + SiLU + act quant, bf16 input (H = 4096) ------------
__global__ __launch_bounds__(256) void ln_silu_quant_kernel(const ushort* __restrict__ h,
                                                            const float* __restrict__ g,
                                                            const float* __restrict__ b,
                                                            int* __restrict__ q,
                                                            float* __restrict__ inv_s) {
    __shared__ float s8[8];
    int row = blockIdx.x;
    int t = threadIdx.x;
    const uint4* hr = (const uint4*)(h + (size_t)row * 4096);
    uint4 p0 = hr[t * 2], p1 = hr[t * 2 + 1];
    float f[16];
    f[0] = bflo(p0.x); f[1] = bfhi(p0.x); f[2] = bflo(p0.y); f[3] = bfhi(p0.y);
    f[4] = bflo(p0.z); f[5] = bfhi(p0.z); f[6] = bflo(p0.w); f[7] = bfhi(p0.w);
    f[8] = bflo(p1.x); f[9] = bfhi(p1.x); f[10] = bflo(p1.y); f[11] = bfhi(p1.y);
    f[12] = bflo(p1.z); f[13] = bfhi(p1.z); f[14] = bflo(p1.w); f[15] = bfhi(p1.w);
    float sum = 0.f, sq = 0.f;
    #pragma unroll
    for (int i = 0; i < 16; i++) { sum += f[i]; sq += f[i] * f[i]; }
    blk_sum2(sum, sq, s8);
    float mu = sum * (1.f / 4096.f);
    float var = sq * (1.f / 4096.f) - mu * mu;
    float rs = rsqrtf(var + EPS);
    const float4* g4 = (const float4*)g;
    const float4* b4 = (const float4*)b;
    float amax = 0.f;
    #pragma unroll
    for (int i = 0; i < 4; i++) {
        float4 gg = g4[t * 4 + i];
        float4 bb = b4[t * 4 + i];
        float y0 = (f[i * 4 + 0] - mu) * rs * gg.x + bb.x;
        float y1 = (f[i * 4 + 1] - mu) * rs * gg.y + bb.y;
        float y2 = (f[i * 4 + 2] - mu) * rs * gg.z + bb.z;
        float y3 = (f[i * 4 + 3] - mu) * rs * gg.w + bb.w;
        f[i * 4 + 0] = y0 / (1.f + expf(-y0));
        f[i * 4 + 1] = y1 / (1.f + expf(-y1));
        f[i * 4 + 2] = y2 / (1.f + expf(-y2));
        f[i * 4 + 3] = y3 / (1.f + expf(-y3));
    }
    #pragma unroll
    for (int i = 0; i < 16; i++) amax = fmaxf(amax, fabsf(f[i]));
    amax = blk_max(amax, s8);
    amax = fmaxf(amax, EPS);
    float scale = 127.f / amax;
    if (t == 0) inv_s[row] = amax / 127.f;
    int4 o;
    o.x = pack4(rintf(f[0] * scale), rintf(f[1] * scale), rintf(f[2] * scale), rintf(f[3] * scale), -128.f, 127.f);
    o.y = pack4(rintf(f[4] * scale), rintf(f[5] * scale), rintf(f[6] * scale), rintf(f[7] * scale), -128.f, 127.f);
    o.z = pack4(rintf(f[8] * scale), rintf(f[9] * scale), rintf(f[10] * scale), rintf(f[11] * scale), -128.f, 127.f);
    o.w = pack4(rintf(f[12] * scale), rintf(f[13] * scale), rintf(f[14] * scale), rintf(f[15] * scale), -128.f, 127.f);
    ((int4*)((char*)q + (size_t)row * 4096))[t] = o;
}

// ---------------- async global->LDS helper ----------------
__device__ __forceinline__ void load_lds16(const void* g, void* l) {
    __builtin_amdgcn_global_load_lds((__attribute__((address_space(1))) void*)(g),
                                     (__attribute__((address_space(3))) void*)(l), 16, 0, 0);
}

// ---------------- 128x128 i8 MFMA GEMM (kept for GEMM3, N=2048) ----------------
template <int MODE>  // 1: final sigmoid epilogue into d_out
__global__ __launch_bounds__(256, 2) void gemm_i8_kernel(
    const char* __restrict__ A, const char* __restrict__ B,
    const float* __restrict__ inv_s, const float* __restrict__ wsum, float invWN,
    int K, void* __restrict__ outp) {
    __shared__ __align__(16) char lA[128 * 128];
    __shared__ __align__(16) char lB[128 * 128];
    const int t = threadIdx.x;
    const int lane = t & 63;
    const int wave = t >> 6;
    const int bm = blockIdx.y * 128, bn = blockIdx.x * 128;
    const int wr = (wave >> 1) * 64, wc = (wave & 1) * 64;

    int32x4 acc[4][4] = {};

    const int r0 = t >> 3;
    const int c0 = (t & 7) * 16;
    const int gcol = c0 ^ (16 * (r0 & 7));
    const char* gA = A + (size_t)(bm + r0) * K + gcol;
    const char* gB = B + (size_t)(bn + r0) * K + gcol;
    char* sA = lA + t * 16;
    char* sB = lB + t * 16;

    const int fr = lane & 15;
    const int fq = lane >> 4;
    const int swz = 16 * (fr & 7);

    for (int k0 = 0; k0 < K; k0 += 128) {
        #pragma unroll
        for (int j = 0; j < 4; j++)
            load_lds16(gA + (size_t)(j * 32) * K + k0, sA + j * 4096);
        #pragma unroll
        for (int j = 0; j < 4; j++)
            load_lds16(gB + (size_t)(j * 32) * K + k0, sB + j * 4096);
        __syncthreads();

        #pragma unroll
        for (int ks = 0; ks < 2; ks++) {
            const int col = (ks * 64 + fq * 16) ^ swz;
            int32x4 af[4], bf[4];
            #pragma unroll
            for (int mt = 0; mt < 4; mt++)
                af[mt] = *(const int32x4*)(lA + (wr + mt * 16 + fr) * 128 + col);
            #pragma unroll
            for (int nt = 0; nt < 4; nt++)
                bf[nt] = *(const int32x4*)(lB + (wc + nt * 16 + fr) * 128 + col);
            #pragma unroll
            for (int mt = 0; mt < 4; mt++) {
                #pragma unroll
                for (int nt = 0; nt < 4; nt++) {
                    acc[mt][nt] = __builtin_amdgcn_mfma_i32_16x16x64_i8(af[mt], bf[nt],
                                                                        acc[mt][nt], 0, 0, 0);
                }
            }
        }
        __syncthreads();
    }

    const float wmean = fmaxf(wsum[0] * invWN, EPS);
    #pragma unroll
    for (int mt = 0; mt < 4; mt++) {
        #pragma unroll
        for (int rg = 0; rg < 4; rg++) {
            int gr = bm + wr + mt * 16 + fq * 4 + rg;
            float rowscale = inv_s[gr] * wmean;
            #pragma unroll
            for (int nt = 0; nt < 4; nt++) {
                int gc = bn + wc + nt * 16 + fr;
                float v = (float)acc[mt][nt][rg] * rowscale;
                if (MODE == 0) {
                    ((__hip_bfloat16*)outp)[(size_t)gr * 4096 + gc] = __float2bfloat16(v);
                } else {
                    if (gc < 2000) {
                        float sg = 1.f / (1.f + expf(-v));
                        float* out = (float*)outp;
                        if (gc < 1000)
                            out[(size_t)gr * 1000 + gc] = sg * 999.f + 1.f;
                        else
                            out[(size_t)4096 * 1000 + (size_t)gr * 1000 + (gc - 1000)] =
                                sg * 100.f;
                    }
                }
            }
        }
    }
}

// ================= 256x256 pipelined i8 GEMM: BK=64B, 4 LDS buffers =================
// 512 threads = 8 waves (2M x 4N); per-wave 128x64 output = acc[8][4].
// 2 phases per K-tile (mh0, mh1), 16 MFMA each. Fragment ds_reads issued ONE PHASE
// AHEAD into alternate register sets, counted lgkmcnt(4)/lgkmcnt(8) waits; staging 3
// tiles ahead with vmcnt(6) once per tile; one s_barrier per phase.
// LDS [256][64] rows carry a 16B-chunk XOR swizzle (chunk ^= (row>>1)&3) applied on
// BOTH sides (pre-swizzled global source for linear global_load_lds dest; same XOR on
// ds_read addr). 8-lane b128 service groups then cover all 8 bank-quads ->
// conflict-free (Round-1 verified: SQ_LDS_BANK_CONFLICT = 0 with this mapping;
// Round-2's linear layout was a 4-way conflict, 6.29M counts).
template <int MH>
__device__ __forceinline__ void mfma_quad(int32x4 (&acc)[8][4], const int32x4 (&af)[4],
                                          const int32x4 (&bf)[4]) {
    #pragma unroll
    for (int i = 0; i < 4; i++) {
        #pragma unroll
        for (int j = 0; j < 4; j++) {
            acc[MH * 4 + i][j] =
                __builtin_amdgcn_mfma_i32_16x16x64_i8(af[i], bf[j], acc[MH * 4 + i][j], 0, 0, 0);
        }
    }
}

__global__ __launch_bounds__(512, 2) void gemm_i8_pipe(
    const char* __restrict__ A, const char* __restrict__ B,
    const float* __restrict__ inv_s, const float* __restrict__ wsum, float invWN,
    int K, __hip_bfloat16* __restrict__ outp) {
    __shared__ __align__(16) char lA[4][256][64];   // 64 KB (4 buffers)
    __shared__ __align__(16) char lB[4][256][64];   // 64 KB
    const int t = threadIdx.x;
    const int lane = t & 63;
    const int wave = t >> 6;

    // T1: bijective XCD swizzle (nwg = 256, divisible by 8)
    const int nwg = gridDim.x * gridDim.y;
    const int wg0 = blockIdx.y * gridDim.x + blockIdx.x;
    const int q8 = nwg >> 3;
    const int wg = (wg0 & 7) * q8 + (wg0 >> 3);
    const int bm = (wg / gridDim.x) * 256;
    const int bn = (wg % gridDim.x) * 256;

    const int wr = (wave >> 2) * 128;   // 2 M-waves
    const int wc = (wave & 3) * 64;     // 4 N-waves
    const int fr = lane & 15;
    const int fq = lane >> 4;

    // staging: thread t -> row t>>2, chunk t&3 (linear LDS dest);
    // global source chunk pre-swizzled by the involution ((t&3) ^ ((t>>3)&3)).
    // Second half (+128 rows) shifts row>>1 by 64 (mult of 4) -> same XOR term.
    const int srow = t >> 2;
    const int schunk = ((t & 3) ^ ((t >> 3) & 3)) * 16;
    const char* gA = A + (size_t)(bm + srow) * K + schunk;
    const char* gB = B + (size_t)(bn + srow) * K + schunk;
    char* sAd = &lA[0][0][0] + t * 16;
    char* sBd = &lB[0][0][0] + t * 16;

    // fragment read bases: row = wr|wc + mh*64 + mt*16 + fr, chunk = fq ^ ((fr>>1)&3)
    // (all row offsets are multiples of 16 rows -> (row>>1)&3 == (fr>>1)&3)
    const int rchunk = (fq ^ ((fr >> 1) & 3)) * 16;
    const char* aRd = &lA[0][0][0] + (wr + fr) * 64 + rchunk;
    const char* bRd = &lB[0][0][0] + (wc + fr) * 64 + rchunk;

    int32x4 acc[8][4] = {};
    int32x4 afX[4], afY[4], bfX[4], bfY[4];
    const int NT = K >> 6;   // BK = 64 bytes

#define STAGE_A(buf, kt) { \
    load_lds16(gA + (size_t)(kt) * 64, sAd + (buf) * 16384); \
    load_lds16(gA + (size_t)128 * K + (size_t)(kt) * 64, sAd + (buf) * 16384 + 8192); }
#define STAGE_B(buf, kt) { \
    load_lds16(gB + (size_t)(kt) * 64, sBd + (buf) * 16384); \
    load_lds16(gB + (size_t)128 * K + (size_t)(kt) * 64, sBd + (buf) * 16384 + 8192); }
#define LD_AF(dst, buf, mh) { \
    const char* p_ = aRd + (buf) * 16384 + (mh) * 4096; \
    dst[0] = *(const int32x4*)(p_); \
    dst[1] = *(const int32x4*)(p_ + 1024); \
    dst[2] = *(const int32x4*)(p_ + 2048); \
    dst[3] = *(const int32x4*)(p_ + 3072); }
#define LD_BF(dst, buf) { \
    const char* p_ = bRd + (buf) * 16384; \
    dst[0] = *(const int32x4*)(p_); \
    dst[1] = *(const int32x4*)(p_ + 1024); \
    dst[2] = *(const int32x4*)(p_ + 2048); \
    dst[3] = *(const int32x4*)(p_ + 3072); }
#define WAITL(n) { asm volatile("s_waitcnt lgkmcnt(" #n ")" ::: "memory"); \
                   __builtin_amdgcn_sched_barrier(0); }
#define WAITV(n) { asm volatile("s_waitcnt vmcnt(" #n ")" ::: "memory"); \
                   __builtin_amdgcn_sched_barrier(0); }
#define BAR() { __builtin_amdgcn_s_barrier(); __builtin_amdgcn_sched_barrier(0); }
#define MF0(afc, bfc) { __builtin_amdgcn_s_setprio(1); mfma_quad<0>(acc, afc, bfc); \
                        __builtin_amdgcn_s_setprio(0); }
#define MF1(afc, bfc) { __builtin_amdgcn_s_setprio(1); mfma_quad<1>(acc, afc, bfc); \
                        __builtin_amdgcn_s_setprio(0); }

    // prologue: stage tiles 0,1,2 into bufs 0,1,2; publish tile 0; issue tile-0 p0 reads
    STAGE_A(0, 0); STAGE_B(0, 0);
    STAGE_A(1, 1); STAGE_B(1, 1);
    STAGE_A(2, 2); STAGE_B(2, 2);
    WAITV(8);
    BAR();
    LD_BF(bfX, 0); LD_AF(afX, 0, 0);   // 8 outstanding lgkm into the loop

    // main loop: 4 tiles per iteration (bufs 0..3 static); consumes tiles 0..NT-5
    for (int kt = 0; kt <= NT - 8; kt += 4) {
        // tile kt+0: buf0, bfX
        STAGE_A(3, kt + 3); LD_AF(afY, 0, 1); WAITL(4); MF0(afX, bfX); WAITV(6); BAR();
        STAGE_B(3, kt + 3); LD_BF(bfY, 1); LD_AF(afX, 1, 0); WAITL(8); MF1(afY, bfX); BAR();
        // tile kt+1: buf1, bfY
        STAGE_A(0, kt + 4); LD_AF(afY, 1, 1); WAITL(4); MF0(afX, bfY); WAITV(6); BAR();
        STAGE_B(0, kt + 4); LD_BF(bfX, 2); LD_AF(afX, 2, 0); WAITL(8); MF1(afY, bfY); BAR();
        // tile kt+2: buf2, bfX
        STAGE_A(1, kt + 5); LD_AF(afY, 2, 1); WAITL(4); MF0(afX, bfX); WAITV(6); BAR();
        STAGE_B(1, kt + 5); LD_BF(bfY, 3); LD_AF(afX, 3, 0); WAITL(8); MF1(afY, bfX); BAR();
        // tile kt+3: buf3, bfY
        STAGE_A(2, kt + 6); LD_AF(afY, 3, 1); WAITL(4); MF0(afX, bfY); WAITV(6); BAR();
        STAGE_B(2, kt + 6); LD_BF(bfX, 0); LD_AF(afX, 0, 0); WAITL(8); MF1(afY, bfY); BAR();
    }

    // epilogue: tiles NT-4..NT-1 (bufs 0..3; NT % 4 == 0 so parity matches)
    // tile NT-4: buf0, bfX (stages the final tile NT-1 into buf3)
    STAGE_A(3, NT - 1); LD_AF(afY, 0, 1); WAITL(4); MF0(afX, bfX); WAITV(6); BAR();
    STAGE_B(3, NT - 1); LD_BF(bfY, 1); LD_AF(afX, 1, 0); WAITL(8); MF1(afY, bfX); BAR();
    // tile NT-3: buf1, bfY
    LD_AF(afY, 1, 1); WAITL(4); MF0(afX, bfY); WAITV(4); BAR();
    LD_BF(bfX, 2); LD_AF(afX, 2, 0); WAITL(8); MF1(afY, bfY); BAR();
    // tile NT-2: buf2, bfX
    LD_AF(afY, 2, 1); WAITL(4); MF0(afX, bfX); WAITV(0); BAR();
    LD_BF(bfY, 3); LD_AF(afX, 3, 0); WAITL(8); MF1(afY, bfX); BAR();
    // tile NT-1: buf3, bfY
    LD_AF(afY, 3, 1); WAITL(4); MF0(afX, bfY); BAR();
    WAITL(0); MF1(afY, bfY);

#undef STAGE_A
#undef STAGE_B
#undef LD_AF
#undef LD_BF
#undef WAITL
#undef WAITV
#undef BAR
#undef MF0
#undef MF1

    const float wmean = fmaxf(wsum[0] * invWN, EPS);
    #pragma unroll
    for (int mt = 0; mt < 8; mt++) {
        #pragma unroll
        for (int rg = 0; rg < 4; rg++) {
            const int gr = bm + wr + mt * 16 + fq * 4 + rg;
            const float rowscale = inv_s[gr] * wmean;
            #pragma unroll
            for (int nt = 0; nt < 4; nt++) {
                const int gc = bn + wc + nt * 16 + fr;
                outp[(size_t)gr * 4096 + gc] =
                    __float2bfloat16((float)acc[mt][nt][rg] * rowscale);
            }
        }
    }
}

// ---------------- host launcher ----------------
extern "C" void kernel_launch(void* const* d_in, const int* in_sizes, int n_in,
                              void* d_out, int out_size, void* d_ws, size_t ws_size,
                              hipStream_t stream) {
    const float* x  = (const float*)d_in[0];
    const float* W0 = (const float*)d_in[1];
    const float* W1 = (const float*)d_in[2];
    const float* W2 = (const float*)d_in[3];
    const float* W3 = (const float*)d_in[4];
    const float* g0 = (const float*)d_in[5];
    const float* b0 = (const float*)d_in[6];
    const float* g1 = (const float*)d_in[7];
    const float* b1 = (const float*)d_in[8];
    const float* g2 = (const float*)d_in[9];
    const float* b2 = (const float*)d_in[10];
    float* out = (float*)d_out;

    char* ws = (char*)d_ws;
    size_t off = 0;
    auto alloc = [&](size_t bytes) -> char* {
        char* p = ws + off;
        off = (off + bytes + 255) & ~(size_t)255;
        return p;
    };
    float* part = (float*)alloc(256 * 16 * sizeof(float));
    float* sums = (float*)alloc(4 * sizeof(float));
    float* inv0 = (float*)alloc(4096 * 4);
    float* inv1 = (float*)alloc(4096 * 4);
    float* inv2 = (float*)alloc(4096 * 4);
    float* inv3 = (float*)alloc(4096 * 4);
    char* wq0 = alloc(4096ll * 1024);
    char* wq1 = alloc(4096ll * 4096);
    char* wq2 = alloc(4096ll * 4096);
    char* wq3 = alloc(2048ll * 4096);
    char* a0  = alloc(4096ll * 1024);
    char* a1  = alloc(4096ll * 4096);
    char* a2  = alloc(4096ll * 4096);
    char* h   = alloc(4096ll * 4096 * 2);
    char* a3 = a1;  // a1 dead after GEMM1; safe sequential reuse

    hipMemsetAsync(part, 0, 256 * 16 * sizeof(float), stream);

    absmean_all_kernel<<<11216, 256, 0, stream>>>(W0, W1, W2, W3, part);
    reduce_sums_kernel<<<1, 256, 0, stream>>>(part, sums);
    actquant_kernel<<<4096, 256, 0, stream>>>(x, (int*)a0, inv0);
    wquant_all_kernel<<<11264, 256, 0, stream>>>(W0, W1, W2, W3, (int*)wq0, (int*)wq1,
                                                 (int*)wq2, (int*)wq3, sums);

    gemm_i8_pipe<<<dim3(16, 16), 512, 0, stream>>>(a0, wq0, inv0, sums + 0,
                                                   1.f / 4194304.f, 1024,
                                                   (__hip_bfloat16*)h);
    ln_silu_quant_kernel<<<4096, 256, 0, stream>>>((const ushort*)h, g0, b0, (int*)a1, inv1);

    gemm_i8_pipe<<<dim3(16, 16), 512, 0, stream>>>(a1, wq1, inv1, sums + 1,
                                                   1.f / 16777216.f, 4096,
                                                   (__hip_bfloat16*)h);
    ln_silu_quant_kernel<<<4096, 256, 0, stream>>>((const ushort*)h, g1, b1, (int*)a2, inv2);

    gemm_i8_pipe<<<dim3(16, 16), 512, 0, stream>>>(a2, wq2, inv2, sums + 2,
                                                   1.f / 16777216.f, 4096,
                                                   (__hip_bfloat16*)h);
    ln_silu_quant_kernel<<<4096, 256, 0, stream>>>((const ushort*)h, g2, b2, (int*)a3, inv3);

    gemm_i8_kernel<1><<<dim3(16, 32), 256, 0, stream>>>(a3, wq3, inv3, sums + 3,
                                                        1.f / 8192000.f, 4096, out);
}